// Round 5
// baseline (1214.050 us; speedup 1.0000x reference)
//
#include <hip/hip_runtime.h>
#include <math.h>

// Problem dims (fixed)
#define N_ 20000
#define E_ 100000
#define B_ 128
#define F_IN_ 14
#define DIM_ 64
#define E_FEAT_ 4
#define MLP_H_ 128
#define EWC_ 4096    // DIM*DIM
#define PC_ 8192     // MLP_H * DIM (P columns)

typedef __attribute__((ext_vector_type(4))) float f32x4;
typedef __attribute__((ext_vector_type(8))) _Float16 halfx8;

// ---------------------------------------------------------------------------
// lin0: out[n,d] = relu(x[n,:] @ lin0_w + b)
__global__ void lin0_kernel(const float* __restrict__ x, const float* __restrict__ w,
                            const float* __restrict__ b, float* __restrict__ out) {
    int idx = blockIdx.x * blockDim.x + threadIdx.x;
    if (idx >= N_ * DIM_) return;
    int n = idx >> 6, d = idx & 63;
    float acc = b[d];
#pragma unroll
    for (int f = 0; f < F_IN_; ++f) acc = fmaf(x[n * F_IN_ + f], w[f * DIM_ + d], acc);
    out[idx] = acc > 0.f ? acc : 0.f;
}

// edge MLP layer 1, written DIRECTLY in src-sorted edge order (via epos):
// h1s[epos[e]*128 + k] = relu(ea[e,:] @ w1 + b1)[k]
__global__ void mlp1_kernel(const float* __restrict__ ea, const float* __restrict__ w1,
                            const float* __restrict__ b1, const int* __restrict__ epos,
                            _Float16* __restrict__ h1s) {
    int idx = blockIdx.x * blockDim.x + threadIdx.x;
    if (idx >= E_ * MLP_H_) return;
    int e = idx >> 7, k = idx & 127;
    float acc = b1[k];
#pragma unroll
    for (int f = 0; f < E_FEAT_; ++f) acc = fmaf(ea[e * E_FEAT_ + f], w1[f * MLP_H_ + k], acc);
    h1s[(size_t)epos[e] * 128 + k] = (_Float16)(acc > 0.f ? acc : 0.f);
}

// degree histograms: outgoing (for src sort) + incoming (for dst sort / mean)
__global__ void deg_kernel(const int* __restrict__ src, const int* __restrict__ dst,
                           int* __restrict__ cnt_src, int* __restrict__ cnt_dst) {
    int e = blockIdx.x * blockDim.x + threadIdx.x;
    if (e >= E_) return;
    atomicAdd(&cnt_src[src[e]], 1);
    atomicAdd(&cnt_dst[dst[e]], 1);
}

// batch is SORTED: off_b[b] = lower_bound(batch, b).
__global__ void batch_off_kernel(const int* __restrict__ batch, int* __restrict__ off_b) {
    int b = threadIdx.x;
    if (b > B_) return;
    int lo = 0, hi = N_;
    while (lo < hi) {
        int mid = (lo + hi) >> 1;
        if (batch[mid] < b) lo = mid + 1; else hi = mid;
    }
    off_b[b] = lo;
}

// exclusive scan over N_ bins -> off[0..N_]
__global__ void scan_bins(const int* __restrict__ cnt, int* __restrict__ off_out) {
    __shared__ int part[256];
    __shared__ int off[257];
    int t = threadIdx.x;
    const int per = (N_ + 255) / 256;
    int base = t * per;
    int s = 0;
    for (int i = 0; i < per; ++i) { int b = base + i; if (b < N_) s += cnt[b]; }
    part[t] = s;
    __syncthreads();
    if (t == 0) {
        int a = 0;
        for (int i = 0; i < 256; ++i) { off[i] = a; a += part[i]; }
        off[256] = a;
    }
    __syncthreads();
    int run = off[t];
    for (int i = 0; i < per; ++i) {
        int b = base + i;
        if (b < N_) { off_out[b] = run; run += cnt[b]; }
    }
    if (t == 0) off_out[N_] = off[256];
}

// scatter edges: epos[e] = src-sorted position; dpos[src-sorted p] = dst-sorted pos
__global__ void scatter_src(const int* __restrict__ src, const int* __restrict__ dst,
                            int* __restrict__ cur, const int* __restrict__ src_off,
                            int* __restrict__ cur_dst, const int* __restrict__ dst_off,
                            int* __restrict__ epos, int* __restrict__ dpos) {
    int e = blockIdx.x * blockDim.x + threadIdx.x;
    if (e >= E_) return;
    int s = src[e];
    int p = src_off[s] + atomicAdd(&cur[s], 1);
    epos[e] = p;
    int d = dst[e];
    int pd = dst_off[d] + atomicAdd(&cur_dst[d], 1);
    dpos[p] = pd;
}

// B prep (once), fp16, TRANSPOSED column order c = o*128 + k:
// Bf[c*64 + i] = (fp16) w2[k*4096 + i*64 + o]
__global__ void prep_b(const float* __restrict__ w2, _Float16* __restrict__ Bf) {
    int idx = blockIdx.x * blockDim.x + threadIdx.x;
    if (idx >= PC_ * 64) return;
    int c = idx >> 6, i = idx & 63;
    int o = c >> 7, k = c & 127;
    Bf[idx] = (_Float16)w2[(size_t)k * EWC_ + i * 64 + o];
}

// ---------------------------------------------------------------------------
// FUSED message kernel (v5): 32 KB LDS -> 4 blocks/CU (occupancy experiment).
// Block = 16 source nodes, 512 threads (8 waves). 8 o-passes of 8 outputs.
// Per pass: GEMM P_part[8 o][16 node][128 k] into LDS (swizzled), then each
// wave computes its 2 nodes' edge messages (h1s x P) and STORES each edge's
// 8 o-values at the edge's dst-sorted slot in msg[] (no atomics).
// Edge MFMA cols 8-15 duplicate 0-7 (reads use lrow&7; stores predicated).
//
// LDS swizzle: addr = o*2048 + node*128 + (k ^ ((node>>2)<<5) ^ (o<<3)), o=0..7.
__global__ __launch_bounds__(512, 8) void fused_msg(
        const float* __restrict__ out, const _Float16* __restrict__ Bf,
        const _Float16* __restrict__ h1s, const float* __restrict__ b2,
        const int* __restrict__ dpos, const int* __restrict__ src_off,
        float* __restrict__ msg) {
    __shared__ _Float16 Plds[8 * 2048];   // 32 KB
    const int tid = threadIdx.x;
    const int lane = tid & 63;
    const int w = __builtin_amdgcn_readfirstlane(tid >> 6);   // 0..7
    const int lrow = lane & 15, quad = lane >> 4;
    const int nb0 = blockIdx.x * 16;

    // GEMM A fragments (16 nodes x K=64), loaded once, reused all 8 passes.
    halfx8 aG[2];
    {
        const float* orow = out + (size_t)(nb0 + lrow) * 64 + quad * 8;
#pragma unroll
        for (int ks = 0; ks < 2; ++ks) {
            float4 v0 = *(const float4*)(orow + ks * 32);
            float4 v1 = *(const float4*)(orow + ks * 32 + 4);
            aG[ks][0] = (_Float16)v0.x; aG[ks][1] = (_Float16)v0.y;
            aG[ks][2] = (_Float16)v0.z; aG[ks][3] = (_Float16)v0.w;
            aG[ks][4] = (_Float16)v1.x; aG[ks][5] = (_Float16)v1.y;
            aG[ks][6] = (_Float16)v1.z; aG[ks][7] = (_Float16)v1.w;
        }
    }

    // Hoisted per-wave node bookkeeping (wave owns nodes 2w, 2w+1).
    const int n0g = nb0 + 2 * w;
    const int beg0 = src_off[n0g];
    const int end0 = src_off[n0g + 1];
    const int end1 = src_off[n0g + 2];

    // Q rows for the 2 nodes: Q[n,o] = sum_i out[n,i]*b2[i*64+o], lane = o.
    float qacc0 = 0.f, qacc1 = 0.f;
    {
        float ov0 = out[(size_t)n0g * 64 + lane];
        float ov1 = out[(size_t)(n0g + 1) * 64 + lane];
#pragma unroll 8
        for (int i = 0; i < 64; ++i) {
            float bv = b2[i * 64 + lane];
            qacc0 = fmaf(__shfl(ov0, i, 64), bv, qacc0);
            qacc1 = fmaf(__shfl(ov1, i, 64), bv, qacc1);
        }
    }

    for (int p = 0; p < 8; ++p) {
        if (p) __syncthreads();   // edge phase of pass p-1 done before overwrite

        // ---- GEMM phase: this wave covers 128 of the pass's 1024 columns ----
#pragma unroll 8
        for (int it = 0; it < 8; ++it) {
            int cl = (w * 8 + it) * 16 + lrow;          // pass-local col 0..1023
            size_t c = (size_t)p * 1024 + cl;           // global Bf column
            halfx8 b0 = *(const halfx8*)&Bf[c * 64 + quad * 8];
            halfx8 b1 = *(const halfx8*)&Bf[c * 64 + 32 + quad * 8];
            f32x4 acc = (f32x4){0.f, 0.f, 0.f, 0.f};
            acc = __builtin_amdgcn_mfma_f32_16x16x32_f16(aG[0], b0, acc, 0, 0, 0);
            acc = __builtin_amdgcn_mfma_f32_16x16x32_f16(aG[1], b1, acc, 0, 0, 0);
            // C-frag: col = lrow (this c), rows = quad*4+rr (nodes). o uniform.
            int o = cl >> 7, k = cl & 127;              // o = 0..7
            int kz = k ^ (quad << 5) ^ (o << 3);        // node>>2 == quad here
            int base = o * 2048 + kz;
#pragma unroll
            for (int rr = 0; rr < 4; ++rr)
                Plds[base + (quad * 4 + rr) * 128] = (_Float16)acc[rr];
        }
        __syncthreads();

        // ---- edge phase for o-chunk [o0, o0+8) ----
        int o0 = p * 8;
#pragma unroll
        for (int nn = 0; nn < 2; ++nn) {
            int nl = 2 * w + nn;                 // node local 0..15
            int beg = nn ? end0 : beg0;
            int endv = nn ? end1 : end0;
            if (beg == endv) continue;
            float qv = __shfl(nn ? qacc1 : qacc0, o0 + (lrow & 7), 64);
            // B-frag: o_loc = lrow&7 (cols 8-15 duplicate), k = ks*32+quad*8+j
            halfx8 bf[4];
#pragma unroll
            for (int ks = 0; ks < 4; ++ks) {
                int kk = (ks * 32 + quad * 8) ^ ((nl >> 2) << 5) ^ ((lrow & 7) << 3);
                bf[ks] = *(const halfx8*)&Plds[(lrow & 7) * 2048 + nl * 128 + kk];
            }
            for (int g = beg; g < endv; g += 16) {
                int gcnt = endv - g; if (gcnt > 16) gcnt = 16;
                int ei = lrow < gcnt ? lrow : gcnt - 1;
                int gi = g + ei;                 // affine, no indirection
                int dpv = dpos[gi];
                halfx8 af[4];
#pragma unroll
                for (int ks = 0; ks < 4; ++ks)
                    af[ks] = *(const halfx8*)&h1s[(size_t)gi * 128 + ks * 32 + quad * 8];
                f32x4 acc = (f32x4){0.f, 0.f, 0.f, 0.f};
#pragma unroll
                for (int ks = 0; ks < 4; ++ks)
                    acc = __builtin_amdgcn_mfma_f32_16x16x32_f16(
                        af[ks], bf[ks], acc, 0, 0, 0);
                // C-frag: col = lrow (valid o for lrow<8), rows = quad*4+rr
#pragma unroll
                for (int rr = 0; rr < 4; ++rr) {
                    int j = quad * 4 + rr;
                    int dp = __shfl(dpv, j, 64);
                    if (j < gcnt && lrow < 8) {
                        msg[(size_t)dp * 64 + o0 + lrow] = acc[rr] + qv;
                    }
                }
            }
        }
    }
}

// combine: segment-sum dst-sorted msgs (NO atomics) + scatter-mean + root +
// bias + relu, then GRU cell.
__global__ __launch_bounds__(256) void gru_kernel(float* __restrict__ out,
                                                  const float* __restrict__ msg,
                                                  const int* __restrict__ dst_off,
                                                  const float* __restrict__ root,
                                                  const float* __restrict__ cbias,
                                                  const float* __restrict__ wi,
                                                  const float* __restrict__ wh,
                                                  const float* __restrict__ bi,
                                                  const float* __restrict__ bh) {
    __shared__ float root_s[64 * 64];
    __shared__ float h_s[32 * 64];
    __shared__ float m_s[32 * 64];
    int tid = threadIdx.x;
    int lane = tid & 63;
    int wv = __builtin_amdgcn_readfirstlane(tid >> 6);
    int nb = blockIdx.x * 32;
#pragma unroll
    for (int it = 0; it < 4; ++it) {
        int i = it * 1024 + tid * 4;
        *(float4*)&root_s[i] = *(const float4*)&root[i];
    }
#pragma unroll
    for (int it = 0; it < 2; ++it) {
        int i = it * 1024 + tid * 4;
        *(float4*)&h_s[i] = *(const float4*)&out[(size_t)nb * 64 + i];
    }
    __syncthreads();

    int nbase = nb + wv * 8;
    float a[8];
#pragma unroll
    for (int j = 0; j < 8; ++j) {
        int n = nbase + j;
        int e0 = dst_off[n], e1 = dst_off[n + 1];   // wave-uniform (scalar)
        float s = 0.f;
        for (int e = e0; e < e1; ++e) s += msg[(size_t)e * 64 + lane];
        float c = (float)(e1 - e0 > 1 ? e1 - e0 : 1);
        a[j] = s / c + cbias[lane];
    }
    for (int i = 0; i < 64; ++i) {
        float rv = root_s[i * 64 + lane];
#pragma unroll
        for (int j = 0; j < 8; ++j)
            a[j] = fmaf(h_s[(wv * 8 + j) * 64 + i], rv, a[j]);
    }
#pragma unroll
    for (int j = 0; j < 8; ++j) {
        float m = a[j] > 0.f ? a[j] : 0.f;
        m_s[(wv * 8 + j) * 64 + lane] = m;
    }
    __syncthreads();

    float gir[8], giz[8], gin[8], ghr[8], ghz[8], ghn[8];
    float bi0 = bi[lane], bi1 = bi[64 + lane], bi2 = bi[128 + lane];
    float bh0 = bh[lane], bh1 = bh[64 + lane], bh2 = bh[128 + lane];
#pragma unroll
    for (int j = 0; j < 8; ++j) {
        gir[j] = bi0; giz[j] = bi1; gin[j] = bi2;
        ghr[j] = bh0; ghz[j] = bh1; ghn[j] = bh2;
    }
    for (int i = 0; i < 64; ++i) {
        float w0 = wi[i * 192 + lane];
        float w1 = wi[i * 192 + 64 + lane];
        float w2v = wi[i * 192 + 128 + lane];
        float u0 = wh[i * 192 + lane];
        float u1 = wh[i * 192 + 64 + lane];
        float u2 = wh[i * 192 + 128 + lane];
#pragma unroll
        for (int j = 0; j < 8; ++j) {
            float mi = m_s[(wv * 8 + j) * 64 + i];
            float hi = h_s[(wv * 8 + j) * 64 + i];
            gir[j] = fmaf(mi, w0, gir[j]);
            giz[j] = fmaf(mi, w1, giz[j]);
            gin[j] = fmaf(mi, w2v, gin[j]);
            ghr[j] = fmaf(hi, u0, ghr[j]);
            ghz[j] = fmaf(hi, u1, ghz[j]);
            ghn[j] = fmaf(hi, u2, ghn[j]);
        }
    }
#pragma unroll
    for (int j = 0; j < 8; ++j) {
        int n = nbase + j;
        float rg = 1.f / (1.f + expf(-(gir[j] + ghr[j])));
        float zg = 1.f / (1.f + expf(-(giz[j] + ghz[j])));
        float ng = tanhf(gin[j] + rg * ghn[j]);
        float h = h_s[(wv * 8 + j) * 64 + lane];
        out[(size_t)n * 64 + lane] = (1.f - zg) * ng + zg * h;
    }
}

// ---------------------------------------------------------------------------
// Fused Set2Set step: LSTM cell -> attention -> q_star update; optional head.
__global__ __launch_bounds__(256) void lstm_attn_kernel(
        const float* __restrict__ out, const int* __restrict__ off_b,
        float* __restrict__ hl, float* __restrict__ cl,
        float* __restrict__ q_star, float* __restrict__ e_ws,
        const float* __restrict__ wi, const float* __restrict__ wh,
        const float* __restrict__ bi, const float* __restrict__ bh,
        const float* __restrict__ hw1, const float* __restrict__ hb1,
        const float* __restrict__ hw2, const float* __restrict__ hb2,
        float* __restrict__ y, int do_head) {
    int b = blockIdx.x;
    int t = threadIdx.x;
    __shared__ float qs[128], hs[64], g[256];
    __shared__ float q[64];
    __shared__ float red[256], racc[256], sasum[4];

    // ---- LSTM cell ----
    if (t < 128) qs[t] = q_star[b * 128 + t];
    if (t < 64) hs[t] = hl[b * 64 + t];
    __syncthreads();
    {
        float acc = bi[t] + bh[t];
#pragma unroll 8
        for (int i = 0; i < 128; ++i) acc = fmaf(qs[i], wi[i * 256 + t], acc);
#pragma unroll 8
        for (int i = 0; i < 64; ++i) acc = fmaf(hs[i], wh[i * 256 + t], acc);
        g[t] = acc;
    }
    __syncthreads();
    if (t < 64) {
        float ig = 1.f / (1.f + expf(-g[t]));
        float fg = 1.f / (1.f + expf(-g[64 + t]));
        float gg = tanhf(g[128 + t]);
        float og = 1.f / (1.f + expf(-g[192 + t]));
        float c = fg * cl[b * 64 + t] + ig * gg;
        cl[b * 64 + t] = c;
        float h = og * tanhf(c);
        hl[b * 64 + t] = h;
        q[t] = h;
    }
    __syncthreads();

    // ---- attention ----
    int start = off_b[b], end = off_b[b + 1];
    float lmax = -1e30f;
    for (int n = start + t; n < end; n += 256) {
        float acc = 0.f;
#pragma unroll 16
        for (int d2 = 0; d2 < 64; ++d2) acc = fmaf(out[n * 64 + d2], q[d2], acc);
        e_ws[n] = acc;
        lmax = fmaxf(lmax, acc);
    }
    red[t] = lmax;
    __syncthreads();
    for (int s2 = 128; s2 > 0; s2 >>= 1) {
        if (t < s2) red[t] = fmaxf(red[t], red[t + s2]);
        __syncthreads();
    }
    float emax = red[0];
    int w = t >> 6, d = t & 63;
    float rl = 0.f, lasum = 0.f;
    for (int n = start + w; n < end; n += 4) {
        float a = expf(e_ws[n] - emax);
        rl = fmaf(a, out[n * 64 + d], rl);
        if (d == 0) lasum += a;
    }
    racc[t] = rl;
    if (d == 0) sasum[w] = lasum;
    __syncthreads();
    if (t < 64) {
        float r = racc[t] + racc[64 + t] + racc[128 + t] + racc[192 + t];
        float as = sasum[0] + sasum[1] + sasum[2] + sasum[3];
        as = fmaxf(as, 1e-16f);
        float rv = r / as;
        q_star[b * 128 + t] = q[t];
        q_star[b * 128 + 64 + t] = rv;
        qs[t] = q[t];
        qs[64 + t] = rv;
    }
    __syncthreads();

    // ---- head (final iteration only) ----
    if (do_head && t < 64) {
        float acc = hb1[t];
#pragma unroll 8
        for (int i = 0; i < 128; ++i) acc = fmaf(qs[i], hw1[i * 64 + t], acc);
        acc = acc > 0.f ? acc : 0.f;
        float p = acc * hw2[t];
        for (int off = 32; off > 0; off >>= 1) p += __shfl_down(p, off, 64);
        if (t == 0) y[b] = p + hb2[0];
    }
}

extern "C" void kernel_launch(void* const* d_in, const int* in_sizes, int n_in,
                              void* d_out, int out_size, void* d_ws, size_t ws_size,
                              hipStream_t stream) {
    (void)in_sizes; (void)n_in; (void)out_size; (void)ws_size;
    const float* x        = (const float*)d_in[0];
    const float* ea       = (const float*)d_in[1];
    const int*   eidx     = (const int*)d_in[2];
    const int*   batch    = (const int*)d_in[3];
    const float* lin0_w   = (const float*)d_in[4];
    const float* lin0_b   = (const float*)d_in[5];
    const float* mlp_w1   = (const float*)d_in[6];
    const float* mlp_b1   = (const float*)d_in[7];
    const float* mlp_w2   = (const float*)d_in[8];
    const float* mlp_b2   = (const float*)d_in[9];
    const float* conv_root= (const float*)d_in[10];
    const float* conv_bias= (const float*)d_in[11];
    const float* gru_wi   = (const float*)d_in[12];
    const float* gru_wh   = (const float*)d_in[13];
    const float* gru_bi   = (const float*)d_in[14];
    const float* gru_bh   = (const float*)d_in[15];
    const float* lstm_wi  = (const float*)d_in[16];
    const float* lstm_wh  = (const float*)d_in[17];
    const float* lstm_bi  = (const float*)d_in[18];
    const float* lstm_bh  = (const float*)d_in[19];
    const float* lin1_w   = (const float*)d_in[20];
    const float* lin1_b   = (const float*)d_in[21];
    const float* lin2_w   = (const float*)d_in[22];
    const float* lin2_b   = (const float*)d_in[23];
    float* y = (float*)d_out;

    const int* src = eidx;
    const int* dst = eidx + E_;

    char* w = (char*)d_ws;
    auto carve = [&](size_t bytes) {
        char* p = w;
        w += (bytes + 255) & ~(size_t)255;
        return p;
    };
    float* out_buf = (float*)carve((size_t)N_ * DIM_ * 4);
    float* e_ws    = (float*)carve((size_t)N_ * 4);
    int*   off_b   = (int*)carve((size_t)(B_ + 1) * 4);
    _Float16* h1s  = (_Float16*)carve((size_t)E_ * MLP_H_ * 2);
    _Float16* Bf   = (_Float16*)carve((size_t)PC_ * 64 * 2);
    int*   src_off = (int*)carve((size_t)(N_ + 1) * 4);
    int*   dst_off = (int*)carve((size_t)(N_ + 1) * 4);
    int*   epos    = (int*)carve((size_t)E_ * 4);
    int*   dpos    = (int*)carve((size_t)E_ * 4);
    float* msg     = (float*)carve((size_t)E_ * DIM_ * 4);   // 25.6 MB, no zeroing
    // contiguous zero zone (single memset)
    char*  zero0   = w;
    int*   cnt_src = (int*)carve((size_t)N_ * 4);
    int*   cnt_dst = (int*)carve((size_t)N_ * 4);
    int*   cur     = (int*)carve((size_t)N_ * 4);
    int*   cur_dst = (int*)carve((size_t)N_ * 4);
    float* q_star  = (float*)carve((size_t)B_ * 128 * 4);
    float* hl      = (float*)carve((size_t)B_ * 64 * 4);
    float* cl      = (float*)carve((size_t)B_ * 64 * 4);
    size_t zbytes  = (size_t)(w - zero0);

    hipMemsetAsync(zero0, 0, zbytes, stream);

    lin0_kernel<<<(N_ * DIM_ + 255) / 256, 256, 0, stream>>>(x, lin0_w, lin0_b, out_buf);
    deg_kernel<<<(E_ + 255) / 256, 256, 0, stream>>>(src, dst, cnt_src, cnt_dst);
    batch_off_kernel<<<1, 256, 0, stream>>>(batch, off_b);
    scan_bins<<<1, 256, 0, stream>>>(cnt_src, src_off);
    scan_bins<<<1, 256, 0, stream>>>(cnt_dst, dst_off);
    scatter_src<<<(E_ + 255) / 256, 256, 0, stream>>>(src, dst, cur, src_off,
                                                      cur_dst, dst_off, epos, dpos);
    mlp1_kernel<<<(E_ * MLP_H_ + 255) / 256, 256, 0, stream>>>(ea, mlp_w1, mlp_b1, epos, h1s);
    prep_b<<<(PC_ * 64 + 255) / 256, 256, 0, stream>>>(mlp_w2, Bf);

    for (int step = 0; step < 3; ++step) {
        fused_msg<<<N_ / 16, 512, 0, stream>>>(out_buf, Bf, h1s, mlp_b2, dpos,
                                               src_off, msg);
        gru_kernel<<<N_ / 32, 256, 0, stream>>>(out_buf, msg, dst_off, conv_root,
                                                conv_bias, gru_wi, gru_wh,
                                                gru_bi, gru_bh);
    }

    for (int s = 0; s < 3; ++s) {
        lstm_attn_kernel<<<B_, 256, 0, stream>>>(out_buf, off_b, hl, cl, q_star, e_ws,
                                                 lstm_wi, lstm_wh, lstm_bi, lstm_bh,
                                                 lin1_w, lin1_b, lin2_w, lin2_b,
                                                 y, s == 2 ? 1 : 0);
    }
}

// Round 7
// 908.614 us; speedup vs baseline: 1.3362x; 1.3362x over previous
//
#include <hip/hip_runtime.h>
#include <math.h>

// Problem dims (fixed)
#define N_ 20000
#define E_ 100000
#define B_ 128
#define F_IN_ 14
#define DIM_ 64
#define E_FEAT_ 4
#define MLP_H_ 128
#define EWC_ 4096    // DIM*DIM
#define PC_ 8192     // MLP_H * DIM (P columns)
#define PC2_ 8256    // PC_ + 64 extra columns holding mlp_b2 (for Q via MFMA)

typedef __attribute__((ext_vector_type(4))) float f32x4;
typedef __attribute__((ext_vector_type(8))) _Float16 halfx8;

// ---------------------------------------------------------------------------
// lin0: out[n,d] = relu(x[n,:] @ lin0_w + b)
__global__ void lin0_kernel(const float* __restrict__ x, const float* __restrict__ w,
                            const float* __restrict__ b, float* __restrict__ out) {
    int idx = blockIdx.x * blockDim.x + threadIdx.x;
    if (idx >= N_ * DIM_) return;
    int n = idx >> 6, d = idx & 63;
    float acc = b[d];
#pragma unroll
    for (int f = 0; f < F_IN_; ++f) acc = fmaf(x[n * F_IN_ + f], w[f * DIM_ + d], acc);
    out[idx] = acc > 0.f ? acc : 0.f;
}

// edge MLP layer 1, written DIRECTLY in src-sorted edge order (via epos):
// h1s[epos[e]*128 + k] = relu(ea[e,:] @ w1 + b1)[k]
__global__ void mlp1_kernel(const float* __restrict__ ea, const float* __restrict__ w1,
                            const float* __restrict__ b1, const int* __restrict__ epos,
                            _Float16* __restrict__ h1s) {
    int idx = blockIdx.x * blockDim.x + threadIdx.x;
    if (idx >= E_ * MLP_H_) return;
    int e = idx >> 7, k = idx & 127;
    float acc = b1[k];
#pragma unroll
    for (int f = 0; f < E_FEAT_; ++f) acc = fmaf(ea[e * E_FEAT_ + f], w1[f * MLP_H_ + k], acc);
    h1s[(size_t)epos[e] * 128 + k] = (_Float16)(acc > 0.f ? acc : 0.f);
}

// degree histograms: incoming (float, for mean) + outgoing (int, for sort)
__global__ void deg_kernel(const int* __restrict__ src, const int* __restrict__ dst,
                           float* __restrict__ cnt, int* __restrict__ cnt_src) {
    int e = blockIdx.x * blockDim.x + threadIdx.x;
    if (e >= E_) return;
    atomicAdd(&cnt[dst[e]], 1.0f);
    atomicAdd(&cnt_src[src[e]], 1);
}

// batch is SORTED: off_b[b] = lower_bound(batch, b).
__global__ void batch_off_kernel(const int* __restrict__ batch, int* __restrict__ off_b) {
    int b = threadIdx.x;
    if (b > B_) return;
    int lo = 0, hi = N_;
    while (lo < hi) {
        int mid = (lo + hi) >> 1;
        if (batch[mid] < b) lo = mid + 1; else hi = mid;
    }
    off_b[b] = lo;
}

// exclusive scan over N_ bins -> src_off[0..N_]
__global__ void scan_src(const int* __restrict__ cnt_src, int* __restrict__ src_off) {
    __shared__ int part[256];
    __shared__ int off[257];
    int t = threadIdx.x;
    const int per = (N_ + 255) / 256;
    int base = t * per;
    int s = 0;
    for (int i = 0; i < per; ++i) { int b = base + i; if (b < N_) s += cnt_src[b]; }
    part[t] = s;
    __syncthreads();
    if (t == 0) {
        int a = 0;
        for (int i = 0; i < 256; ++i) { off[i] = a; a += part[i]; }
        off[256] = a;
    }
    __syncthreads();
    int run = off[t];
    for (int i = 0; i < per; ++i) {
        int b = base + i;
        if (b < N_) { src_off[b] = run; run += cnt_src[b]; }
    }
    if (t == 0) src_off[N_] = off[256];
}

// scatter edges into src-sorted order: record position (epos) + sorted dst
__global__ void scatter_src(const int* __restrict__ src, const int* __restrict__ dst,
                            int* __restrict__ cur, const int* __restrict__ src_off,
                            int* __restrict__ epos, int* __restrict__ dsts) {
    int e = blockIdx.x * blockDim.x + threadIdx.x;
    if (e >= E_) return;
    int s = src[e];
    int p = src_off[s] + atomicAdd(&cur[s], 1);
    epos[e] = p;
    dsts[p] = dst[e];
}

// B prep (once), fp16, TRANSPOSED column order c = o*128 + k:
// Bf[c*64 + i] = (fp16) w2[k*4096 + i*64 + o], c < 8192.
// Extra cols c = 8192 + o hold mlp_b2: Bf[c*64 + i] = b2[i*64 + o]
// (so Q = out @ b2-matrix runs on the same MFMA path as P).
__global__ void prep_b(const float* __restrict__ w2, const float* __restrict__ b2,
                       _Float16* __restrict__ Bf) {
    int idx = blockIdx.x * blockDim.x + threadIdx.x;
    if (idx >= PC2_ * 64) return;
    int c = idx >> 6, i = idx & 63;
    if (c < PC_) {
        int o = c >> 7, k = c & 127;
        Bf[idx] = (_Float16)w2[(size_t)k * EWC_ + i * 64 + o];
    } else {
        int o = c - PC_;
        Bf[idx] = (_Float16)b2[i * 64 + o];
    }
}

// ---------------------------------------------------------------------------
// FUSED message kernel (v6): r2 structure (atomicAdd agg) + r4 swizzle +
// Q via MFMA (no serial shuffle loop).
// Block = 16 source nodes, 512 threads (8 waves). 4 o-passes of 16 outputs.
// Per pass: GEMM P_part[16 o][16 node][128 k] into LDS (swizzled), then each
// wave computes its 2 nodes' edge messages (h1s x P) and atomically
// accumulates msg+Q into agg[dst].
//
// LDS swizzle: addr = o*2048 + node*128 + (k ^ ((node>>2)<<5) ^ ((o&7)<<3)).
__global__ __launch_bounds__(512, 4) void fused_msg(
        const float* __restrict__ out, const _Float16* __restrict__ Bf,
        const _Float16* __restrict__ h1s,
        const int* __restrict__ dsts, const int* __restrict__ src_off,
        float* __restrict__ agg) {
    __shared__ _Float16 Plds[16 * 2048];   // 64 KB
    const int tid = threadIdx.x;
    const int lane = tid & 63;
    const int w = __builtin_amdgcn_readfirstlane(tid >> 6);   // 0..7
    const int lrow = lane & 15, quad = lane >> 4;
    const int nb0 = blockIdx.x * 16;

    // GEMM A fragments (16 nodes x K=64), loaded once, reused all 4 passes.
    halfx8 aG[2];
    {
        const float* orow = out + (size_t)(nb0 + lrow) * 64 + quad * 8;
#pragma unroll
        for (int ks = 0; ks < 2; ++ks) {
            float4 v0 = *(const float4*)(orow + ks * 32);
            float4 v1 = *(const float4*)(orow + ks * 32 + 4);
            aG[ks][0] = (_Float16)v0.x; aG[ks][1] = (_Float16)v0.y;
            aG[ks][2] = (_Float16)v0.z; aG[ks][3] = (_Float16)v0.w;
            aG[ks][4] = (_Float16)v1.x; aG[ks][5] = (_Float16)v1.y;
            aG[ks][6] = (_Float16)v1.z; aG[ks][7] = (_Float16)v1.w;
        }
    }

    // Q via MFMA: qf[f][r] = Q[node = quad*4+r][o = f*16 + lrow]
    f32x4 qf[4];
#pragma unroll
    for (int f = 0; f < 4; ++f) {
        const _Float16* bc = &Bf[(size_t)(PC_ + f * 16 + lrow) * 64 + quad * 8];
        halfx8 bq0 = *(const halfx8*)bc;
        halfx8 bq1 = *(const halfx8*)(bc + 32);
        f32x4 z = (f32x4){0.f, 0.f, 0.f, 0.f};
        z = __builtin_amdgcn_mfma_f32_16x16x32_f16(aG[0], bq0, z, 0, 0, 0);
        z = __builtin_amdgcn_mfma_f32_16x16x32_f16(aG[1], bq1, z, 0, 0, 0);
        qf[f] = z;
    }

    // Hoisted per-wave node bookkeeping (wave owns nodes 2w, 2w+1).
    const int n0g = nb0 + 2 * w;
    const int beg0 = src_off[n0g];
    const int end0 = src_off[n0g + 1];
    const int end1 = src_off[n0g + 2];

#pragma unroll
    for (int p = 0; p < 4; ++p) {
        if (p) __syncthreads();   // edge phase of pass p-1 done before overwrite

        // ---- GEMM phase: this wave covers 256 of the pass's 2048 columns ----
#pragma unroll 8
        for (int nf = 0; nf < 16; ++nf) {
            int cl = w * 256 + nf * 16 + lrow;          // pass-local col 0..2047
            size_t c = (size_t)(p * 2048 + cl);
            halfx8 b0 = *(const halfx8*)&Bf[c * 64 + quad * 8];
            halfx8 b1 = *(const halfx8*)&Bf[c * 64 + 32 + quad * 8];
            f32x4 acc = (f32x4){0.f, 0.f, 0.f, 0.f};
            acc = __builtin_amdgcn_mfma_f32_16x16x32_f16(aG[0], b0, acc, 0, 0, 0);
            acc = __builtin_amdgcn_mfma_f32_16x16x32_f16(aG[1], b1, acc, 0, 0, 0);
            // C-frag: col = lrow (this c), rows = quad*4+rr (nodes). o uniform.
            int o = cl >> 7, k = cl & 127;
            int kz = k ^ (quad << 5) ^ ((o & 7) << 3);  // node>>2 == quad here
            int base = o * 2048 + kz;
#pragma unroll
            for (int rr = 0; rr < 4; ++rr)
                Plds[base + (quad * 4 + rr) * 128] = (_Float16)acc[rr];
        }
        __syncthreads();

        // ---- edge phase for o-chunk [o0, o0+16) ----
        int o0 = p * 16;
#pragma unroll
        for (int nn = 0; nn < 2; ++nn) {
            int nl = 2 * w + nn;                 // node local 0..15
            int beg = nn ? end0 : beg0;
            int endv = nn ? end1 : end0;
            if (beg == endv) continue;
            // qv = Q[nb0+nl][o0+lrow], fetched from the holding lane of qf[p]
            int srcl = ((nl >> 2) << 4) | lrow;
            int rsel = nl & 3;
            float qel = rsel == 0 ? qf[p][0] : rsel == 1 ? qf[p][1]
                      : rsel == 2 ? qf[p][2] : qf[p][3];
            float qv = __shfl(qel, srcl, 64);
            // B-frag: col = lrow (o), k = ks*32 + quad*8 + j, from swizzled LDS
            halfx8 bf[4];
#pragma unroll
            for (int ks = 0; ks < 4; ++ks) {
                int kk = (ks * 32 + quad * 8) ^ ((nl >> 2) << 5) ^ ((lrow & 7) << 3);
                bf[ks] = *(const halfx8*)&Plds[lrow * 2048 + nl * 128 + kk];
            }
            for (int g = beg; g < endv; g += 16) {
                int gcnt = endv - g; if (gcnt > 16) gcnt = 16;
                int ei = lrow < gcnt ? lrow : gcnt - 1;
                int gi = g + ei;                 // affine, no indirection
                int dv = dsts[gi];
                halfx8 af[4];
#pragma unroll
                for (int ks = 0; ks < 4; ++ks)
                    af[ks] = *(const halfx8*)&h1s[(size_t)gi * 128 + ks * 32 + quad * 8];
                f32x4 acc = (f32x4){0.f, 0.f, 0.f, 0.f};
#pragma unroll
                for (int ks = 0; ks < 4; ++ks)
                    acc = __builtin_amdgcn_mfma_f32_16x16x32_f16(
                        af[ks], bf[ks], acc, 0, 0, 0);
                // C-frag: col = lrow (o), rows = quad*4+rr (edges)
#pragma unroll
                for (int rr = 0; rr < 4; ++rr) {
                    int j = quad * 4 + rr;
                    int d = __shfl(dv, j, 64);
                    if (j < gcnt) {
                        atomicAdd(&agg[(size_t)d * 64 + o0 + lrow], acc[rr] + qv);
                    }
                }
            }
        }
    }
}

// combine (scatter-mean + root + bias + relu) and GRU cell.
// Also RESETS agg to zero after consuming it (free re-init for next step).
__global__ __launch_bounds__(256) void gru_kernel(float* __restrict__ out,
                                                  float* __restrict__ agg,
                                                  const float* __restrict__ cnt,
                                                  const float* __restrict__ root,
                                                  const float* __restrict__ cbias,
                                                  const float* __restrict__ wi,
                                                  const float* __restrict__ wh,
                                                  const float* __restrict__ bi,
                                                  const float* __restrict__ bh) {
    __shared__ float root_s[64 * 64];
    __shared__ float h_s[32 * 64];
    __shared__ float m_s[32 * 64];
    int tid = threadIdx.x;
    int lane = tid & 63;
    int wv = __builtin_amdgcn_readfirstlane(tid >> 6);
    int nb = blockIdx.x * 32;
#pragma unroll
    for (int it = 0; it < 4; ++it) {
        int i = it * 1024 + tid * 4;
        *(float4*)&root_s[i] = *(const float4*)&root[i];
    }
#pragma unroll
    for (int it = 0; it < 2; ++it) {
        int i = it * 1024 + tid * 4;
        *(float4*)&h_s[i] = *(const float4*)&out[(size_t)nb * 64 + i];
    }
    __syncthreads();

    int nbase = nb + wv * 8;
    float a[8];
#pragma unroll
    for (int j = 0; j < 8; ++j) {
        int n = nbase + j;
        float c = cnt[n]; c = c > 1.f ? c : 1.f;
        a[j] = agg[(size_t)n * 64 + lane] / c + cbias[lane];
        agg[(size_t)n * 64 + lane] = 0.f;   // re-zero for next step
    }
    for (int i = 0; i < 64; ++i) {
        float rv = root_s[i * 64 + lane];
#pragma unroll
        for (int j = 0; j < 8; ++j)
            a[j] = fmaf(h_s[(wv * 8 + j) * 64 + i], rv, a[j]);
    }
#pragma unroll
    for (int j = 0; j < 8; ++j) {
        float m = a[j] > 0.f ? a[j] : 0.f;
        m_s[(wv * 8 + j) * 64 + lane] = m;
    }
    __syncthreads();

    float gir[8], giz[8], gin[8], ghr[8], ghz[8], ghn[8];
    float bi0 = bi[lane], bi1 = bi[64 + lane], bi2 = bi[128 + lane];
    float bh0 = bh[lane], bh1 = bh[64 + lane], bh2 = bh[128 + lane];
#pragma unroll
    for (int j = 0; j < 8; ++j) {
        gir[j] = bi0; giz[j] = bi1; gin[j] = bi2;
        ghr[j] = bh0; ghz[j] = bh1; ghn[j] = bh2;
    }
    for (int i = 0; i < 64; ++i) {
        float w0 = wi[i * 192 + lane];
        float w1 = wi[i * 192 + 64 + lane];
        float w2v = wi[i * 192 + 128 + lane];
        float u0 = wh[i * 192 + lane];
        float u1 = wh[i * 192 + 64 + lane];
        float u2 = wh[i * 192 + 128 + lane];
#pragma unroll
        for (int j = 0; j < 8; ++j) {
            float mi = m_s[(wv * 8 + j) * 64 + i];
            float hi = h_s[(wv * 8 + j) * 64 + i];
            gir[j] = fmaf(mi, w0, gir[j]);
            giz[j] = fmaf(mi, w1, giz[j]);
            gin[j] = fmaf(mi, w2v, gin[j]);
            ghr[j] = fmaf(hi, u0, ghr[j]);
            ghz[j] = fmaf(hi, u1, ghz[j]);
            ghn[j] = fmaf(hi, u2, ghn[j]);
        }
    }
#pragma unroll
    for (int j = 0; j < 8; ++j) {
        int n = nbase + j;
        float rg = 1.f / (1.f + expf(-(gir[j] + ghr[j])));
        float zg = 1.f / (1.f + expf(-(giz[j] + ghz[j])));
        float ng = tanhf(gin[j] + rg * ghn[j]);
        float h = h_s[(wv * 8 + j) * 64 + lane];
        out[(size_t)n * 64 + lane] = (1.f - zg) * ng + zg * h;
    }
}

// ---------------------------------------------------------------------------
// Fused Set2Set step: LSTM cell -> attention -> q_star update; optional head.
__global__ __launch_bounds__(256) void lstm_attn_kernel(
        const float* __restrict__ out, const int* __restrict__ off_b,
        float* __restrict__ hl, float* __restrict__ cl,
        float* __restrict__ q_star, float* __restrict__ e_ws,
        const float* __restrict__ wi, const float* __restrict__ wh,
        const float* __restrict__ bi, const float* __restrict__ bh,
        const float* __restrict__ hw1, const float* __restrict__ hb1,
        const float* __restrict__ hw2, const float* __restrict__ hb2,
        float* __restrict__ y, int do_head) {
    int b = blockIdx.x;
    int t = threadIdx.x;
    __shared__ float qs[128], hs[64], g[256];
    __shared__ float q[64];
    __shared__ float red[256], racc[256], sasum[4];

    // ---- LSTM cell ----
    if (t < 128) qs[t] = q_star[b * 128 + t];
    if (t < 64) hs[t] = hl[b * 64 + t];
    __syncthreads();
    {
        float acc = bi[t] + bh[t];
#pragma unroll 8
        for (int i = 0; i < 128; ++i) acc = fmaf(qs[i], wi[i * 256 + t], acc);
#pragma unroll 8
        for (int i = 0; i < 64; ++i) acc = fmaf(hs[i], wh[i * 256 + t], acc);
        g[t] = acc;
    }
    __syncthreads();
    if (t < 64) {
        float ig = 1.f / (1.f + expf(-g[t]));
        float fg = 1.f / (1.f + expf(-g[64 + t]));
        float gg = tanhf(g[128 + t]);
        float og = 1.f / (1.f + expf(-g[192 + t]));
        float c = fg * cl[b * 64 + t] + ig * gg;
        cl[b * 64 + t] = c;
        float h = og * tanhf(c);
        hl[b * 64 + t] = h;
        q[t] = h;
    }
    __syncthreads();

    // ---- attention ----
    int start = off_b[b], end = off_b[b + 1];
    float lmax = -1e30f;
    for (int n = start + t; n < end; n += 256) {
        float acc = 0.f;
#pragma unroll 16
        for (int d2 = 0; d2 < 64; ++d2) acc = fmaf(out[n * 64 + d2], q[d2], acc);
        e_ws[n] = acc;
        lmax = fmaxf(lmax, acc);
    }
    red[t] = lmax;
    __syncthreads();
    for (int s2 = 128; s2 > 0; s2 >>= 1) {
        if (t < s2) red[t] = fmaxf(red[t], red[t + s2]);
        __syncthreads();
    }
    float emax = red[0];
    int w = t >> 6, d = t & 63;
    float rl = 0.f, lasum = 0.f;
    for (int n = start + w; n < end; n += 4) {
        float a = expf(e_ws[n] - emax);
        rl = fmaf(a, out[n * 64 + d], rl);
        if (d == 0) lasum += a;
    }
    racc[t] = rl;
    if (d == 0) sasum[w] = lasum;
    __syncthreads();
    if (t < 64) {
        float r = racc[t] + racc[64 + t] + racc[128 + t] + racc[192 + t];
        float as = sasum[0] + sasum[1] + sasum[2] + sasum[3];
        as = fmaxf(as, 1e-16f);
        float rv = r / as;
        q_star[b * 128 + t] = q[t];
        q_star[b * 128 + 64 + t] = rv;
        qs[t] = q[t];
        qs[64 + t] = rv;
    }
    __syncthreads();

    // ---- head (final iteration only) ----
    if (do_head && t < 64) {
        float acc = hb1[t];
#pragma unroll 8
        for (int i = 0; i < 128; ++i) acc = fmaf(qs[i], hw1[i * 64 + t], acc);
        acc = acc > 0.f ? acc : 0.f;
        float p = acc * hw2[t];
        for (int off = 32; off > 0; off >>= 1) p += __shfl_down(p, off, 64);
        if (t == 0) y[b] = p + hb2[0];
    }
}

extern "C" void kernel_launch(void* const* d_in, const int* in_sizes, int n_in,
                              void* d_out, int out_size, void* d_ws, size_t ws_size,
                              hipStream_t stream) {
    (void)in_sizes; (void)n_in; (void)out_size; (void)ws_size;
    const float* x        = (const float*)d_in[0];
    const float* ea       = (const float*)d_in[1];
    const int*   eidx     = (const int*)d_in[2];
    const int*   batch    = (const int*)d_in[3];
    const float* lin0_w   = (const float*)d_in[4];
    const float* lin0_b   = (const float*)d_in[5];
    const float* mlp_w1   = (const float*)d_in[6];
    const float* mlp_b1   = (const float*)d_in[7];
    const float* mlp_w2   = (const float*)d_in[8];
    const float* mlp_b2   = (const float*)d_in[9];
    const float* conv_root= (const float*)d_in[10];
    const float* conv_bias= (const float*)d_in[11];
    const float* gru_wi   = (const float*)d_in[12];
    const float* gru_wh   = (const float*)d_in[13];
    const float* gru_bi   = (const float*)d_in[14];
    const float* gru_bh   = (const float*)d_in[15];
    const float* lstm_wi  = (const float*)d_in[16];
    const float* lstm_wh  = (const float*)d_in[17];
    const float* lstm_bi  = (const float*)d_in[18];
    const float* lstm_bh  = (const float*)d_in[19];
    const float* lin1_w   = (const float*)d_in[20];
    const float* lin1_b   = (const float*)d_in[21];
    const float* lin2_w   = (const float*)d_in[22];
    const float* lin2_b   = (const float*)d_in[23];
    float* y = (float*)d_out;

    const int* src = eidx;
    const int* dst = eidx + E_;

    char* w = (char*)d_ws;
    auto carve = [&](size_t bytes) {
        char* p = w;
        w += (bytes + 255) & ~(size_t)255;
        return p;
    };
    float* out_buf = (float*)carve((size_t)N_ * DIM_ * 4);
    float* e_ws    = (float*)carve((size_t)N_ * 4);
    int*   off_b   = (int*)carve((size_t)(B_ + 1) * 4);
    _Float16* h1s  = (_Float16*)carve((size_t)E_ * MLP_H_ * 2);
    _Float16* Bf   = (_Float16*)carve((size_t)PC2_ * 64 * 2);
    int*   src_off = (int*)carve((size_t)(N_ + 1) * 4);
    int*   epos    = (int*)carve((size_t)E_ * 4);
    int*   dsts    = (int*)carve((size_t)E_ * 4);
    // contiguous zero zone (single memset)
    char*  zero0   = w;
    float* agg     = (float*)carve((size_t)N_ * DIM_ * 4);
    float* cnt     = (float*)carve((size_t)N_ * 4);
    int*   cnt_src = (int*)carve((size_t)N_ * 4);
    int*   cur     = (int*)carve((size_t)N_ * 4);
    float* q_star  = (float*)carve((size_t)B_ * 128 * 4);
    float* hl      = (float*)carve((size_t)B_ * 64 * 4);
    float* cl      = (float*)carve((size_t)B_ * 64 * 4);
    size_t zbytes  = (size_t)(w - zero0);

    hipMemsetAsync(zero0, 0, zbytes, stream);

    lin0_kernel<<<(N_ * DIM_ + 255) / 256, 256, 0, stream>>>(x, lin0_w, lin0_b, out_buf);
    deg_kernel<<<(E_ + 255) / 256, 256, 0, stream>>>(src, dst, cnt, cnt_src);
    batch_off_kernel<<<1, 256, 0, stream>>>(batch, off_b);
    scan_src<<<1, 256, 0, stream>>>(cnt_src, src_off);
    scatter_src<<<(E_ + 255) / 256, 256, 0, stream>>>(src, dst, cur, src_off, epos, dsts);
    mlp1_kernel<<<(E_ * MLP_H_ + 255) / 256, 256, 0, stream>>>(ea, mlp_w1, mlp_b1, epos, h1s);
    prep_b<<<(PC2_ * 64 + 255) / 256, 256, 0, stream>>>(mlp_w2, mlp_b2, Bf);

    for (int step = 0; step < 3; ++step) {
        fused_msg<<<N_ / 16, 512, 0, stream>>>(out_buf, Bf, h1s, dsts,
                                               src_off, agg);
        gru_kernel<<<N_ / 32, 256, 0, stream>>>(out_buf, agg, cnt, conv_root, conv_bias,
                                                gru_wi, gru_wh, gru_bi, gru_bh);
    }

    for (int s = 0; s < 3; ++s) {
        lstm_attn_kernel<<<B_, 256, 0, stream>>>(out_buf, off_b, hl, cl, q_star, e_ws,
                                                 lstm_wi, lstm_wh, lstm_bi, lstm_bh,
                                                 lin1_w, lin1_b, lin2_w, lin2_b,
                                                 y, s == 2 ? 1 : 0);
    }
}

// Round 8
// 603.891 us; speedup vs baseline: 2.0104x; 1.5046x over previous
//
#include <hip/hip_runtime.h>
#include <math.h>

// Problem dims (fixed)
#define N_ 20000
#define E_ 100000
#define B_ 128
#define F_IN_ 14
#define DIM_ 64
#define E_FEAT_ 4
#define MLP_H_ 128
#define EWC_ 4096    // DIM*DIM
#define PC_ 8192     // MLP_H * DIM (P columns)
#define PC2_ 8256    // PC_ + 64 extra columns holding mlp_b2 (for Q via MFMA)

typedef __attribute__((ext_vector_type(4))) float f32x4;
typedef __attribute__((ext_vector_type(8))) _Float16 halfx8;

// ---------------------------------------------------------------------------
// lin0: out[n,d] = relu(x[n,:] @ lin0_w + b)
__global__ void lin0_kernel(const float* __restrict__ x, const float* __restrict__ w,
                            const float* __restrict__ b, float* __restrict__ out) {
    int idx = blockIdx.x * blockDim.x + threadIdx.x;
    if (idx >= N_ * DIM_) return;
    int n = idx >> 6, d = idx & 63;
    float acc = b[d];
#pragma unroll
    for (int f = 0; f < F_IN_; ++f) acc = fmaf(x[n * F_IN_ + f], w[f * DIM_ + d], acc);
    out[idx] = acc > 0.f ? acc : 0.f;
}

// edge MLP layer 1, written DIRECTLY in src-sorted edge order (via epos):
// h1s[epos[e]*128 + k] = relu(ea[e,:] @ w1 + b1)[k]
__global__ void mlp1_kernel(const float* __restrict__ ea, const float* __restrict__ w1,
                            const float* __restrict__ b1, const int* __restrict__ epos,
                            _Float16* __restrict__ h1s) {
    int idx = blockIdx.x * blockDim.x + threadIdx.x;
    if (idx >= E_ * MLP_H_) return;
    int e = idx >> 7, k = idx & 127;
    float acc = b1[k];
#pragma unroll
    for (int f = 0; f < E_FEAT_; ++f) acc = fmaf(ea[e * E_FEAT_ + f], w1[f * MLP_H_ + k], acc);
    h1s[(size_t)epos[e] * 128 + k] = (_Float16)(acc > 0.f ? acc : 0.f);
}

// degree histograms: incoming (float, for mean) + outgoing (int, for sort)
__global__ void deg_kernel(const int* __restrict__ src, const int* __restrict__ dst,
                           float* __restrict__ cnt, int* __restrict__ cnt_src) {
    int e = blockIdx.x * blockDim.x + threadIdx.x;
    if (e >= E_) return;
    atomicAdd(&cnt[dst[e]], 1.0f);
    atomicAdd(&cnt_src[src[e]], 1);
}

// batch is SORTED: off_b[b] = lower_bound(batch, b).
__global__ void batch_off_kernel(const int* __restrict__ batch, int* __restrict__ off_b) {
    int b = threadIdx.x;
    if (b > B_) return;
    int lo = 0, hi = N_;
    while (lo < hi) {
        int mid = (lo + hi) >> 1;
        if (batch[mid] < b) lo = mid + 1; else hi = mid;
    }
    off_b[b] = lo;
}

// exclusive scan over N_ bins -> src_off[0..N_]
__global__ void scan_src(const int* __restrict__ cnt_src, int* __restrict__ src_off) {
    __shared__ int part[256];
    __shared__ int off[257];
    int t = threadIdx.x;
    const int per = (N_ + 255) / 256;
    int base = t * per;
    int s = 0;
    for (int i = 0; i < per; ++i) { int b = base + i; if (b < N_) s += cnt_src[b]; }
    part[t] = s;
    __syncthreads();
    if (t == 0) {
        int a = 0;
        for (int i = 0; i < 256; ++i) { off[i] = a; a += part[i]; }
        off[256] = a;
    }
    __syncthreads();
    int run = off[t];
    for (int i = 0; i < per; ++i) {
        int b = base + i;
        if (b < N_) { src_off[b] = run; run += cnt_src[b]; }
    }
    if (t == 0) src_off[N_] = off[256];
}

// scatter edges into src-sorted order: record position (epos) + sorted dst
__global__ void scatter_src(const int* __restrict__ src, const int* __restrict__ dst,
                            int* __restrict__ cur, const int* __restrict__ src_off,
                            int* __restrict__ epos, int* __restrict__ dsts) {
    int e = blockIdx.x * blockDim.x + threadIdx.x;
    if (e >= E_) return;
    int s = src[e];
    int p = src_off[s] + atomicAdd(&cur[s], 1);
    epos[e] = p;
    dsts[p] = dst[e];
}

// B prep (once), fp16, WAVE-COALESCED TILED layout.
// Logical column c (c = o*128 + k for c < 8192; c = 8192 + o holds mlp_b2),
// row i (0..63). Stored so that a wave's 64 lanes (lane = quad*16 + lrow)
// reading fragment (c16 = c>>4, ks) load ONE contiguous 1 KB burst:
//   pos = c16*1024 + ks*512 + quad*128 + lrow*8 + j
// where lrow = c & 15, i = ks*32 + quad*8 + j.
__global__ void prep_b(const float* __restrict__ w2, const float* __restrict__ b2,
                       _Float16* __restrict__ Bf) {
    int idx = blockIdx.x * blockDim.x + threadIdx.x;
    if (idx >= PC2_ * 64) return;
    int c16 = idx >> 10;
    int r   = idx & 1023;
    int ks  = r >> 9;
    int q   = (r >> 7) & 3;
    int lr  = (r >> 3) & 15;
    int j   = r & 7;
    int c = c16 * 16 + lr;
    int i = ks * 32 + q * 8 + j;
    float v;
    if (c < PC_) {
        int o = c >> 7, k = c & 127;
        v = w2[(size_t)k * EWC_ + i * 64 + o];
    } else {
        int o = c - PC_;
        v = b2[i * 64 + o];
    }
    Bf[idx] = (_Float16)v;
}

// ---------------------------------------------------------------------------
// FUSED message kernel (v8): identical arithmetic/structure to v6/v7, but the
// Bf stream is read through the coalesced tiled layout — each B-fragment load
// is one contiguous 1 KB wave burst (8 full-line L2 requests) instead of 16
// stride-128B sector requests. Targets the L2 request-rate wall.
//
// Block = 16 source nodes, 512 threads (8 waves). 4 o-passes of 16 outputs.
// LDS swizzle: addr = o*2048 + node*128 + (k ^ ((node>>2)<<5) ^ ((o&7)<<3)).
__global__ __launch_bounds__(512, 4) void fused_msg(
        const float* __restrict__ out, const _Float16* __restrict__ Bf,
        const _Float16* __restrict__ h1s,
        const int* __restrict__ dsts, const int* __restrict__ src_off,
        float* __restrict__ agg) {
    __shared__ _Float16 Plds[16 * 2048];   // 64 KB
    const int tid = threadIdx.x;
    const int lane = tid & 63;
    const int w = __builtin_amdgcn_readfirstlane(tid >> 6);   // 0..7
    const int lrow = lane & 15, quad = lane >> 4;
    const int nb0 = blockIdx.x * 16;

    // GEMM A fragments (16 nodes x K=64), loaded once, reused all 4 passes.
    halfx8 aG[2];
    {
        const float* orow = out + (size_t)(nb0 + lrow) * 64 + quad * 8;
#pragma unroll
        for (int ks = 0; ks < 2; ++ks) {
            float4 v0 = *(const float4*)(orow + ks * 32);
            float4 v1 = *(const float4*)(orow + ks * 32 + 4);
            aG[ks][0] = (_Float16)v0.x; aG[ks][1] = (_Float16)v0.y;
            aG[ks][2] = (_Float16)v0.z; aG[ks][3] = (_Float16)v0.w;
            aG[ks][4] = (_Float16)v1.x; aG[ks][5] = (_Float16)v1.y;
            aG[ks][6] = (_Float16)v1.z; aG[ks][7] = (_Float16)v1.w;
        }
    }

    // Q via MFMA: qf[f][r] = Q[node = quad*4+r][o = f*16 + lrow]
    f32x4 qf[4];
#pragma unroll
    for (int f = 0; f < 4; ++f) {
        const _Float16* bc = &Bf[(size_t)(512 + f) * 1024 + quad * 128 + lrow * 8];
        halfx8 bq0 = *(const halfx8*)bc;
        halfx8 bq1 = *(const halfx8*)(bc + 512);
        f32x4 z = (f32x4){0.f, 0.f, 0.f, 0.f};
        z = __builtin_amdgcn_mfma_f32_16x16x32_f16(aG[0], bq0, z, 0, 0, 0);
        z = __builtin_amdgcn_mfma_f32_16x16x32_f16(aG[1], bq1, z, 0, 0, 0);
        qf[f] = z;
    }

    // Hoisted per-wave node bookkeeping (wave owns nodes 2w, 2w+1).
    const int n0g = nb0 + 2 * w;
    const int beg0 = src_off[n0g];
    const int end0 = src_off[n0g + 1];
    const int end1 = src_off[n0g + 2];

#pragma unroll
    for (int p = 0; p < 4; ++p) {
        if (p) __syncthreads();   // edge phase of pass p-1 done before overwrite

        // ---- GEMM phase: this wave covers 256 of the pass's 2048 columns ----
#pragma unroll 8
        for (int nf = 0; nf < 16; ++nf) {
            int cl = w * 256 + nf * 16 + lrow;          // pass-local col 0..2047
            // c16 tile index: lanes of this instr share one contiguous tile.
            size_t tb = (size_t)(p * 128 + w * 16 + nf) * 1024 + quad * 128 + lrow * 8;
            halfx8 b0 = *(const halfx8*)&Bf[tb];
            halfx8 b1 = *(const halfx8*)&Bf[tb + 512];
            f32x4 acc = (f32x4){0.f, 0.f, 0.f, 0.f};
            acc = __builtin_amdgcn_mfma_f32_16x16x32_f16(aG[0], b0, acc, 0, 0, 0);
            acc = __builtin_amdgcn_mfma_f32_16x16x32_f16(aG[1], b1, acc, 0, 0, 0);
            // C-frag: col = lrow (this c), rows = quad*4+rr (nodes). o uniform.
            int o = cl >> 7, k = cl & 127;
            int kz = k ^ (quad << 5) ^ ((o & 7) << 3);  // node>>2 == quad here
            int base = o * 2048 + kz;
#pragma unroll
            for (int rr = 0; rr < 4; ++rr)
                Plds[base + (quad * 4 + rr) * 128] = (_Float16)acc[rr];
        }
        __syncthreads();

        // ---- edge phase for o-chunk [o0, o0+16) ----
        int o0 = p * 16;
#pragma unroll
        for (int nn = 0; nn < 2; ++nn) {
            int nl = 2 * w + nn;                 // node local 0..15
            int beg = nn ? end0 : beg0;
            int endv = nn ? end1 : end0;
            if (beg == endv) continue;
            // qv = Q[nb0+nl][o0+lrow], fetched from the holding lane of qf[p]
            int srcl = ((nl >> 2) << 4) | lrow;
            int rsel = nl & 3;
            float qel = rsel == 0 ? qf[p][0] : rsel == 1 ? qf[p][1]
                      : rsel == 2 ? qf[p][2] : qf[p][3];
            float qv = __shfl(qel, srcl, 64);
            // B-frag: col = lrow (o), k = ks*32 + quad*8 + j, from swizzled LDS
            halfx8 bf[4];
#pragma unroll
            for (int ks = 0; ks < 4; ++ks) {
                int kk = (ks * 32 + quad * 8) ^ ((nl >> 2) << 5) ^ ((lrow & 7) << 3);
                bf[ks] = *(const halfx8*)&Plds[lrow * 2048 + nl * 128 + kk];
            }
            for (int g = beg; g < endv; g += 16) {
                int gcnt = endv - g; if (gcnt > 16) gcnt = 16;
                int ei = lrow < gcnt ? lrow : gcnt - 1;
                int gi = g + ei;                 // affine, no indirection
                int dv = dsts[gi];
                halfx8 af[4];
#pragma unroll
                for (int ks = 0; ks < 4; ++ks)
                    af[ks] = *(const halfx8*)&h1s[(size_t)gi * 128 + ks * 32 + quad * 8];
                f32x4 acc = (f32x4){0.f, 0.f, 0.f, 0.f};
#pragma unroll
                for (int ks = 0; ks < 4; ++ks)
                    acc = __builtin_amdgcn_mfma_f32_16x16x32_f16(
                        af[ks], bf[ks], acc, 0, 0, 0);
                // C-frag: col = lrow (o), rows = quad*4+rr (edges)
#pragma unroll
                for (int rr = 0; rr < 4; ++rr) {
                    int j = quad * 4 + rr;
                    int d = __shfl(dv, j, 64);
                    if (j < gcnt) {
                        atomicAdd(&agg[(size_t)d * 64 + o0 + lrow], acc[rr] + qv);
                    }
                }
            }
        }
    }
}

// combine (scatter-mean + root + bias + relu) and GRU cell.
// Also RESETS agg to zero after consuming it (free re-init for next step).
__global__ __launch_bounds__(256) void gru_kernel(float* __restrict__ out,
                                                  float* __restrict__ agg,
                                                  const float* __restrict__ cnt,
                                                  const float* __restrict__ root,
                                                  const float* __restrict__ cbias,
                                                  const float* __restrict__ wi,
                                                  const float* __restrict__ wh,
                                                  const float* __restrict__ bi,
                                                  const float* __restrict__ bh) {
    __shared__ float root_s[64 * 64];
    __shared__ float h_s[32 * 64];
    __shared__ float m_s[32 * 64];
    int tid = threadIdx.x;
    int lane = tid & 63;
    int wv = __builtin_amdgcn_readfirstlane(tid >> 6);
    int nb = blockIdx.x * 32;
#pragma unroll
    for (int it = 0; it < 4; ++it) {
        int i = it * 1024 + tid * 4;
        *(float4*)&root_s[i] = *(const float4*)&root[i];
    }
#pragma unroll
    for (int it = 0; it < 2; ++it) {
        int i = it * 1024 + tid * 4;
        *(float4*)&h_s[i] = *(const float4*)&out[(size_t)nb * 64 + i];
    }
    __syncthreads();

    int nbase = nb + wv * 8;
    float a[8];
#pragma unroll
    for (int j = 0; j < 8; ++j) {
        int n = nbase + j;
        float c = cnt[n]; c = c > 1.f ? c : 1.f;
        a[j] = agg[(size_t)n * 64 + lane] / c + cbias[lane];
        agg[(size_t)n * 64 + lane] = 0.f;   // re-zero for next step
    }
    for (int i = 0; i < 64; ++i) {
        float rv = root_s[i * 64 + lane];
#pragma unroll
        for (int j = 0; j < 8; ++j)
            a[j] = fmaf(h_s[(wv * 8 + j) * 64 + i], rv, a[j]);
    }
#pragma unroll
    for (int j = 0; j < 8; ++j) {
        float m = a[j] > 0.f ? a[j] : 0.f;
        m_s[(wv * 8 + j) * 64 + lane] = m;
    }
    __syncthreads();

    float gir[8], giz[8], gin[8], ghr[8], ghz[8], ghn[8];
    float bi0 = bi[lane], bi1 = bi[64 + lane], bi2 = bi[128 + lane];
    float bh0 = bh[lane], bh1 = bh[64 + lane], bh2 = bh[128 + lane];
#pragma unroll
    for (int j = 0; j < 8; ++j) {
        gir[j] = bi0; giz[j] = bi1; gin[j] = bi2;
        ghr[j] = bh0; ghz[j] = bh1; ghn[j] = bh2;
    }
    for (int i = 0; i < 64; ++i) {
        float w0 = wi[i * 192 + lane];
        float w1 = wi[i * 192 + 64 + lane];
        float w2v = wi[i * 192 + 128 + lane];
        float u0 = wh[i * 192 + lane];
        float u1 = wh[i * 192 + 64 + lane];
        float u2 = wh[i * 192 + 128 + lane];
#pragma unroll
        for (int j = 0; j < 8; ++j) {
            float mi = m_s[(wv * 8 + j) * 64 + i];
            float hi = h_s[(wv * 8 + j) * 64 + i];
            gir[j] = fmaf(mi, w0, gir[j]);
            giz[j] = fmaf(mi, w1, giz[j]);
            gin[j] = fmaf(mi, w2v, gin[j]);
            ghr[j] = fmaf(hi, u0, ghr[j]);
            ghz[j] = fmaf(hi, u1, ghz[j]);
            ghn[j] = fmaf(hi, u2, ghn[j]);
        }
    }
#pragma unroll
    for (int j = 0; j < 8; ++j) {
        int n = nbase + j;
        float rg = 1.f / (1.f + expf(-(gir[j] + ghr[j])));
        float zg = 1.f / (1.f + expf(-(giz[j] + ghz[j])));
        float ng = tanhf(gin[j] + rg * ghn[j]);
        float h = h_s[(wv * 8 + j) * 64 + lane];
        out[(size_t)n * 64 + lane] = (1.f - zg) * ng + zg * h;
    }
}

// ---------------------------------------------------------------------------
// Fused Set2Set step: LSTM cell -> attention -> q_star update; optional head.
__global__ __launch_bounds__(256) void lstm_attn_kernel(
        const float* __restrict__ out, const int* __restrict__ off_b,
        float* __restrict__ hl, float* __restrict__ cl,
        float* __restrict__ q_star, float* __restrict__ e_ws,
        const float* __restrict__ wi, const float* __restrict__ wh,
        const float* __restrict__ bi, const float* __restrict__ bh,
        const float* __restrict__ hw1, const float* __restrict__ hb1,
        const float* __restrict__ hw2, const float* __restrict__ hb2,
        float* __restrict__ y, int do_head) {
    int b = blockIdx.x;
    int t = threadIdx.x;
    __shared__ float qs[128], hs[64], g[256];
    __shared__ float q[64];
    __shared__ float red[256], racc[256], sasum[4];

    // ---- LSTM cell ----
    if (t < 128) qs[t] = q_star[b * 128 + t];
    if (t < 64) hs[t] = hl[b * 64 + t];
    __syncthreads();
    {
        float acc = bi[t] + bh[t];
#pragma unroll 8
        for (int i = 0; i < 128; ++i) acc = fmaf(qs[i], wi[i * 256 + t], acc);
#pragma unroll 8
        for (int i = 0; i < 64; ++i) acc = fmaf(hs[i], wh[i * 256 + t], acc);
        g[t] = acc;
    }
    __syncthreads();
    if (t < 64) {
        float ig = 1.f / (1.f + expf(-g[t]));
        float fg = 1.f / (1.f + expf(-g[64 + t]));
        float gg = tanhf(g[128 + t]);
        float og = 1.f / (1.f + expf(-g[192 + t]));
        float c = fg * cl[b * 64 + t] + ig * gg;
        cl[b * 64 + t] = c;
        float h = og * tanhf(c);
        hl[b * 64 + t] = h;
        q[t] = h;
    }
    __syncthreads();

    // ---- attention ----
    int start = off_b[b], end = off_b[b + 1];
    float lmax = -1e30f;
    for (int n = start + t; n < end; n += 256) {
        float acc = 0.f;
#pragma unroll 16
        for (int d2 = 0; d2 < 64; ++d2) acc = fmaf(out[n * 64 + d2], q[d2], acc);
        e_ws[n] = acc;
        lmax = fmaxf(lmax, acc);
    }
    red[t] = lmax;
    __syncthreads();
    for (int s2 = 128; s2 > 0; s2 >>= 1) {
        if (t < s2) red[t] = fmaxf(red[t], red[t + s2]);
        __syncthreads();
    }
    float emax = red[0];
    int w = t >> 6, d = t & 63;
    float rl = 0.f, lasum = 0.f;
    for (int n = start + w; n < end; n += 4) {
        float a = expf(e_ws[n] - emax);
        rl = fmaf(a, out[n * 64 + d], rl);
        if (d == 0) lasum += a;
    }
    racc[t] = rl;
    if (d == 0) sasum[w] = lasum;
    __syncthreads();
    if (t < 64) {
        float r = racc[t] + racc[64 + t] + racc[128 + t] + racc[192 + t];
        float as = sasum[0] + sasum[1] + sasum[2] + sasum[3];
        as = fmaxf(as, 1e-16f);
        float rv = r / as;
        q_star[b * 128 + t] = q[t];
        q_star[b * 128 + 64 + t] = rv;
        qs[t] = q[t];
        qs[64 + t] = rv;
    }
    __syncthreads();

    // ---- head (final iteration only) ----
    if (do_head && t < 64) {
        float acc = hb1[t];
#pragma unroll 8
        for (int i = 0; i < 128; ++i) acc = fmaf(qs[i], hw1[i * 64 + t], acc);
        acc = acc > 0.f ? acc : 0.f;
        float p = acc * hw2[t];
        for (int off = 32; off > 0; off >>= 1) p += __shfl_down(p, off, 64);
        if (t == 0) y[b] = p + hb2[0];
    }
}

extern "C" void kernel_launch(void* const* d_in, const int* in_sizes, int n_in,
                              void* d_out, int out_size, void* d_ws, size_t ws_size,
                              hipStream_t stream) {
    (void)in_sizes; (void)n_in; (void)out_size; (void)ws_size;
    const float* x        = (const float*)d_in[0];
    const float* ea       = (const float*)d_in[1];
    const int*   eidx     = (const int*)d_in[2];
    const int*   batch    = (const int*)d_in[3];
    const float* lin0_w   = (const float*)d_in[4];
    const float* lin0_b   = (const float*)d_in[5];
    const float* mlp_w1   = (const float*)d_in[6];
    const float* mlp_b1   = (const float*)d_in[7];
    const float* mlp_w2   = (const float*)d_in[8];
    const float* mlp_b2   = (const float*)d_in[9];
    const float* conv_root= (const float*)d_in[10];
    const float* conv_bias= (const float*)d_in[11];
    const float* gru_wi   = (const float*)d_in[12];
    const float* gru_wh   = (const float*)d_in[13];
    const float* gru_bi   = (const float*)d_in[14];
    const float* gru_bh   = (const float*)d_in[15];
    const float* lstm_wi  = (const float*)d_in[16];
    const float* lstm_wh  = (const float*)d_in[17];
    const float* lstm_bi  = (const float*)d_in[18];
    const float* lstm_bh  = (const float*)d_in[19];
    const float* lin1_w   = (const float*)d_in[20];
    const float* lin1_b   = (const float*)d_in[21];
    const float* lin2_w   = (const float*)d_in[22];
    const float* lin2_b   = (const float*)d_in[23];
    float* y = (float*)d_out;

    const int* src = eidx;
    const int* dst = eidx + E_;

    char* w = (char*)d_ws;
    auto carve = [&](size_t bytes) {
        char* p = w;
        w += (bytes + 255) & ~(size_t)255;
        return p;
    };
    float* out_buf = (float*)carve((size_t)N_ * DIM_ * 4);
    float* e_ws    = (float*)carve((size_t)N_ * 4);
    int*   off_b   = (int*)carve((size_t)(B_ + 1) * 4);
    _Float16* h1s  = (_Float16*)carve((size_t)E_ * MLP_H_ * 2);
    _Float16* Bf   = (_Float16*)carve((size_t)PC2_ * 64 * 2);
    int*   src_off = (int*)carve((size_t)(N_ + 1) * 4);
    int*   epos    = (int*)carve((size_t)E_ * 4);
    int*   dsts    = (int*)carve((size_t)E_ * 4);
    // contiguous zero zone (single memset)
    char*  zero0   = w;
    float* agg     = (float*)carve((size_t)N_ * DIM_ * 4);
    float* cnt     = (float*)carve((size_t)N_ * 4);
    int*   cnt_src = (int*)carve((size_t)N_ * 4);
    int*   cur     = (int*)carve((size_t)N_ * 4);
    float* q_star  = (float*)carve((size_t)B_ * 128 * 4);
    float* hl      = (float*)carve((size_t)B_ * 64 * 4);
    float* cl      = (float*)carve((size_t)B_ * 64 * 4);
    size_t zbytes  = (size_t)(w - zero0);

    hipMemsetAsync(zero0, 0, zbytes, stream);

    lin0_kernel<<<(N_ * DIM_ + 255) / 256, 256, 0, stream>>>(x, lin0_w, lin0_b, out_buf);
    deg_kernel<<<(E_ + 255) / 256, 256, 0, stream>>>(src, dst, cnt, cnt_src);
    batch_off_kernel<<<1, 256, 0, stream>>>(batch, off_b);
    scan_src<<<1, 256, 0, stream>>>(cnt_src, src_off);
    scatter_src<<<(E_ + 255) / 256, 256, 0, stream>>>(src, dst, cur, src_off, epos, dsts);
    mlp1_kernel<<<(E_ * MLP_H_ + 255) / 256, 256, 0, stream>>>(ea, mlp_w1, mlp_b1, epos, h1s);
    prep_b<<<(PC2_ * 64 + 255) / 256, 256, 0, stream>>>(mlp_w2, mlp_b2, Bf);

    for (int step = 0; step < 3; ++step) {
        fused_msg<<<N_ / 16, 512, 0, stream>>>(out_buf, Bf, h1s, dsts,
                                               src_off, agg);
        gru_kernel<<<N_ / 32, 256, 0, stream>>>(out_buf, agg, cnt, conv_root, conv_bias,
                                                gru_wi, gru_wh, gru_bi, gru_bh);
    }

    for (int s = 0; s < 3; ++s) {
        lstm_attn_kernel<<<B_, 256, 0, stream>>>(out_buf, off_b, hl, cl, q_star, e_ws,
                                                 lstm_wi, lstm_wh, lstm_bi, lstm_bh,
                                                 lin1_w, lin1_b, lin2_w, lin2_b,
                                                 y, s == 2 ? 1 : 0);
    }
}